// Round 4
// baseline (2389.637 us; speedup 1.0000x reference)
//
#include <hip/hip_runtime.h>
#include <hip/hip_bf16.h>
#include <stdint.h>

#define NN 100000
#define NE 1600000

typedef __attribute__((ext_vector_type(4))) float f32x4;
typedef __attribute__((ext_vector_type(8))) __bf16 bf16x8;
typedef __attribute__((ext_vector_type(8))) short s16x8;
typedef __attribute__((ext_vector_type(4))) unsigned int u32x4;

__device__ __forceinline__ unsigned short f2bf(float f) {
  unsigned int u = __builtin_bit_cast(unsigned int, f);
  u += 0x7fffu + ((u >> 16) & 1u);
  return (unsigned short)(u >> 16);
}

__device__ __forceinline__ f32x4 mfma16(bf16x8 a, bf16x8 b, f32x4 c) {
  return __builtin_amdgcn_mfma_f32_16x16x32_bf16(a, b, c, 0, 0, 0);
}

// ---------------------------------------------------------------------------
// setup: convert msg weights + global to bf16 (edge kernel only)
// ---------------------------------------------------------------------------
__global__ void convert_kernel(const float* __restrict__ w1, const float* __restrict__ w2,
                               const float* __restrict__ g,
                               unsigned short* __restrict__ w1b, unsigned short* __restrict__ w2b,
                               unsigned short* __restrict__ gb)
{
  const int tid = blockIdx.x * 256 + threadIdx.x;
  if (tid < 256 * 128) w1b[tid] = f2bf(w1[tid]);
  if (tid < 128 * 128) w2b[tid] = f2bf(w2[tid]);
  if (tid < 64) gb[tid] = f2bf(g[tid]);
}

// ---------------------------------------------------------------------------
// CSR build: histogram -> exclusive scan -> position scatter
// ---------------------------------------------------------------------------
__global__ void hist_kernel(const int* __restrict__ ei, int* __restrict__ cnt)
{
  int i = blockIdx.x * 256 + threadIdx.x;
  const int stride = gridDim.x * 256;
  for (; i < NE; i += stride) atomicAdd(&cnt[ei[NE + i]], 1);
}

__global__ __launch_bounds__(1024) void scan_kernel(const int* __restrict__ cnt,
                                                    int* __restrict__ row_start,
                                                    int* __restrict__ cursor)
{
  __shared__ int part[1024];
  const int t = threadIdx.x;
  const int chunk = (NN + 1023) / 1024;  // 98
  const int base = t * chunk;
  int s = 0;
  for (int i = 0; i < chunk; ++i) {
    const int idx = base + i;
    if (idx < NN) s += cnt[idx];
  }
  part[t] = s;
  __syncthreads();
  // Hillis-Steele inclusive scan over 1024 partials
  for (int off = 1; off < 1024; off <<= 1) {
    int v = (t >= off) ? part[t - off] : 0;
    __syncthreads();
    part[t] += v;
    __syncthreads();
  }
  int run = (t == 0) ? 0 : part[t - 1];
  for (int i = 0; i < chunk; ++i) {
    const int idx = base + i;
    if (idx < NN) {
      row_start[idx] = run;
      cursor[idx] = run;
      run += cnt[idx];
    }
  }
}

__global__ void scatter_kernel(const int* __restrict__ ei, int* __restrict__ cursor,
                               int* __restrict__ csr)
{
  int i = blockIdx.x * 256 + threadIdx.x;
  const int stride = gridDim.x * 256;
  for (; i < NE; i += stride) {
    const int d = ei[NE + i];
    const int pos = atomicAdd(&cursor[d], 1);
    csr[pos] = i;
  }
}

// ---------------------------------------------------------------------------
// edge kernel (CSR order): messages = MLP(concat(node[src], edge_state, gs))
// 64 dst-sorted edges per tile -> segmented sum in LDS -> ~1 atomic per run.
// ---------------------------------------------------------------------------
__global__ __launch_bounds__(256, 3) void edge_kernel(
    const int* __restrict__ ei,
    const float* __restrict__ edge_state,
    const float* __restrict__ node_state,
    const int* __restrict__ csr,
    const unsigned short* __restrict__ w1b,
    const unsigned short* __restrict__ w2b,
    const float* __restrict__ bias1g,
    const float* __restrict__ bias2g,
    const unsigned short* __restrict__ gb,
    float* __restrict__ agg)
{
  __shared__ unsigned short sX[64 * 256];  // 32 KB; reused as f32 msg tile [64][128]
  __shared__ unsigned short sH[64 * 128];  // 16 KB
  __shared__ int sDst[64];
  __shared__ int sEid[64];
  float* sMsgF = (float*)sX;

  const int t = threadIdx.x;
  const int lane = t & 63;
  const int wv = t >> 6;
  const int l15 = lane & 15;
  const int lq = lane >> 4;

  // preload W1/W2 B-fragments into registers (per-wave column slice)
  bf16x8 b1f[8][2], b2f[4][2];
  float bs1[2], bs2[2];
  for (int n = 0; n < 2; ++n) {
    const int col = wv * 32 + n * 16 + l15;
    bs1[n] = bias1g[col];
    bs2[n] = bias2g[col];
    for (int ks = 0; ks < 8; ++ks) {
      const int k0 = ks * 32 + lq * 8;
      s16x8 v;
#pragma unroll
      for (int j = 0; j < 8; ++j) v[j] = (short)w1b[(k0 + j) * 128 + col];
      b1f[ks][n] = __builtin_bit_cast(bf16x8, v);
    }
    for (int ks = 0; ks < 4; ++ks) {
      const int k0 = ks * 32 + lq * 8;
      s16x8 v;
#pragma unroll
      for (int j = 0; j < 8; ++j) v[j] = (short)w2b[(k0 + j) * 128 + col];
      b2f[ks][n] = __builtin_bit_cast(bf16x8, v);
    }
  }

  const int r = t >> 2;   // edge row within tile
  const int p = t & 3;    // quarter of the row
  const int rs = r & 7;   // swizzle key

  for (int tile = blockIdx.x; tile < NE / 64; tile += gridDim.x) {
    __syncthreads();  // protect LDS from previous iteration's consumers
    if (t < 64) sEid[t] = csr[tile * 64 + t];
    __syncthreads();

    // ---- stage ----
    const int e = sEid[r];
    const int src = ei[e];
    if (p == 0) sDst[r] = ei[NE + e];
    {  // node gather (f32 -> bf16): chunks 0..15
      const f32x4* nsv = (const f32x4*)(node_state + (size_t)src * 128 + p * 32);
#pragma unroll
      for (int j = 0; j < 4; ++j) {
        f32x4 x0 = nsv[2 * j], x1 = nsv[2 * j + 1];
        unsigned short buf[8];
#pragma unroll
        for (int i = 0; i < 4; ++i) { buf[i] = f2bf(x0[i]); buf[4 + i] = f2bf(x1[i]); }
        const int c = p * 4 + j;
        *(u32x4*)((char*)sX + r * 512 + ((c ^ rs) * 16)) = *(u32x4*)buf;
      }
    }
    {  // edge_state: f32 -> bf16, chunks 16..23
      const f32x4* es = (const f32x4*)(edge_state + (size_t)e * 64 + p * 16);
      f32x4 e0v = es[0], e1v = es[1], e2v = es[2], e3v = es[3];
      unsigned short bufa[8], bufb[8];
#pragma unroll
      for (int i = 0; i < 4; ++i) {
        bufa[i] = f2bf(e0v[i]); bufa[4 + i] = f2bf(e1v[i]);
        bufb[i] = f2bf(e2v[i]); bufb[4 + i] = f2bf(e3v[i]);
      }
      const int c = 16 + 2 * p;
      *(u32x4*)((char*)sX + r * 512 + ((c ^ rs) * 16)) = *(u32x4*)bufa;
      *(u32x4*)((char*)sX + r * 512 + (((c + 1) ^ rs) * 16)) = *(u32x4*)bufb;
    }
    {  // global (pre-converted bf16): chunks 24..31
      const u32x4* g = (const u32x4*)(gb + p * 16);
      const int c = 24 + 2 * p;
      *(u32x4*)((char*)sX + r * 512 + ((c ^ rs) * 16)) = g[0];
      *(u32x4*)((char*)sX + r * 512 + (((c + 1) ^ rs) * 16)) = g[1];
    }
    __syncthreads();

    // ---- phase 1: h1 = relu(X @ W1 + b1) ----
    f32x4 acc[4][2];
#pragma unroll
    for (int m = 0; m < 4; ++m)
#pragma unroll
      for (int n = 0; n < 2; ++n)
        acc[m][n] = (f32x4){bs1[n], bs1[n], bs1[n], bs1[n]};
#pragma unroll
    for (int ks = 0; ks < 8; ++ks) {
      bf16x8 a[4];
#pragma unroll
      for (int m = 0; m < 4; ++m) {
        const int row = m * 16 + l15;
        a[m] = *(const bf16x8*)((const char*)sX + row * 512 + (((4 * ks + lq) ^ (row & 7)) * 16));
      }
#pragma unroll
      for (int m = 0; m < 4; ++m)
#pragma unroll
        for (int n = 0; n < 2; ++n)
          acc[m][n] = mfma16(a[m], b1f[ks][n], acc[m][n]);
    }
    // relu + store h1 (swizzled bf16 [64][128])
#pragma unroll
    for (int m = 0; m < 4; ++m)
#pragma unroll
      for (int n = 0; n < 2; ++n)
#pragma unroll
        for (int i = 0; i < 4; ++i) {
          const int row = m * 16 + lq * 4 + i;
          const int col = wv * 32 + n * 16 + l15;
          float v = acc[m][n][i];
          v = v > 0.f ? v : 0.f;
          *(unsigned short*)((char*)sH + row * 256 +
                             ((((col >> 3) ^ (row & 7)) * 16) + (col & 7) * 2)) = f2bf(v);
        }
    __syncthreads();

    // ---- phase 2: msg = h1 @ W2 + b2 -> f32 LDS tile (XOR-swizzled) ----
    f32x4 acc2[4][2];
#pragma unroll
    for (int m = 0; m < 4; ++m)
#pragma unroll
      for (int n = 0; n < 2; ++n)
        acc2[m][n] = (f32x4){bs2[n], bs2[n], bs2[n], bs2[n]};
#pragma unroll
    for (int ks = 0; ks < 4; ++ks) {
      bf16x8 a[4];
#pragma unroll
      for (int m = 0; m < 4; ++m) {
        const int row = m * 16 + l15;
        a[m] = *(const bf16x8*)((const char*)sH + row * 256 + (((4 * ks + lq) ^ (row & 7)) * 16));
      }
#pragma unroll
      for (int m = 0; m < 4; ++m)
#pragma unroll
        for (int n = 0; n < 2; ++n)
          acc2[m][n] = mfma16(a[m], b2f[ks][n], acc2[m][n]);
    }
#pragma unroll
    for (int m = 0; m < 4; ++m)
#pragma unroll
      for (int n = 0; n < 2; ++n)
#pragma unroll
        for (int i = 0; i < 4; ++i) {
          const int row = m * 16 + lq * 4 + i;
          const int col = wv * 32 + n * 16 + l15;
          sMsgF[row * 128 + (col ^ row)] = acc2[m][n][i];  // row<64 -> col^row<128
        }
    __syncthreads();

    // ---- segmented sum over dst runs (dst-sorted tile) ----
    {
      const int col = t & 127;
      const int base = (t >> 7) * 32;
      float run = 0.f;
      int prevd = sDst[base];           // wave-uniform branch pattern
      for (int j = 0; j < 32; ++j) {
        const int rr = base + j;
        const int d = sDst[rr];
        if (d != prevd) {
          atomicAdd(&agg[(size_t)prevd * 128 + col], run);
          run = 0.f;
          prevd = d;
        }
        run += sMsgF[rr * 128 + (col ^ rr)];
      }
      atomicAdd(&agg[(size_t)prevd * 128 + col], run);
    }
  }
}

// ---------------------------------------------------------------------------
// update MLP phase 1 in full f32 (VALU): h1 = relu(X @ U1 + b1), K = 320
// ---------------------------------------------------------------------------
__global__ __launch_bounds__(128, 3) void upd1_kernel(
    const float* __restrict__ node_state,
    const float* __restrict__ agg,
    const int* __restrict__ cnt,
    const float* __restrict__ u1,    // [320][128] f32
    const float* __restrict__ b1,
    const float* __restrict__ gs,    // [64] f32
    float* __restrict__ h1out)
{
  const int n = blockIdx.x * 128 + threadIdx.x;
  const bool act = n < NN;
  const size_t row = (size_t)(act ? n : 0) * 128;

  f32x4 acc[32];
#pragma unroll
  for (int c = 0; c < 32; ++c) acc[c] = *(const f32x4*)(b1 + 4 * c);

  const float rdeg = act ? (1.0f / (float)max(cnt[n], 1)) : 0.0f;

  // node part: k = 0..127
  for (int k4 = 0; k4 < 32; ++k4) {
    const f32x4 x = *(const f32x4*)(node_state + row + 4 * k4);
#pragma unroll
    for (int kk = 0; kk < 4; ++kk) {
      const float xk = x[kk];
      const float* wr = u1 + (size_t)(4 * k4 + kk) * 128;
#pragma unroll
      for (int c = 0; c < 32; ++c) acc[c] += xk * *(const f32x4*)(wr + 4 * c);
    }
  }
  // aggregated part: k = 128..255
  for (int k4 = 0; k4 < 32; ++k4) {
    const f32x4 x = *(const f32x4*)(agg + row + 4 * k4);
#pragma unroll
    for (int kk = 0; kk < 4; ++kk) {
      const float xk = x[kk] * rdeg;
      const float* wr = u1 + (size_t)(128 + 4 * k4 + kk) * 128;
#pragma unroll
      for (int c = 0; c < 32; ++c) acc[c] += xk * *(const f32x4*)(wr + 4 * c);
    }
  }
  // global part: k = 256..319 (uniform xk)
  for (int k = 0; k < 64; ++k) {
    const float xk = gs[k];
    const float* wr = u1 + (size_t)(256 + k) * 128;
#pragma unroll
    for (int c = 0; c < 32; ++c) acc[c] += xk * *(const f32x4*)(wr + 4 * c);
  }

  if (act) {
    float* o = h1out + (size_t)n * 128;
#pragma unroll
    for (int c = 0; c < 32; ++c) {
      f32x4 v = acc[c];
#pragma unroll
      for (int i = 0; i < 4; ++i) v[i] = v[i] > 0.f ? v[i] : 0.f;
      *(f32x4*)(o + 4 * c) = v;
    }
  }
}

// ---------------------------------------------------------------------------
// update MLP phase 2 + residual + LayerNorm, full f32 (VALU)
// ---------------------------------------------------------------------------
__global__ __launch_bounds__(128, 3) void upd2_kernel(
    const float* __restrict__ node_state,
    const float* __restrict__ h1,
    const float* __restrict__ u2,    // [128][128] f32
    const float* __restrict__ b2,
    const float* __restrict__ lng,
    const float* __restrict__ lnb,
    float* __restrict__ out)
{
  const int n = blockIdx.x * 128 + threadIdx.x;
  const bool act = n < NN;
  const size_t row = (size_t)(act ? n : 0) * 128;

  f32x4 acc[32];
#pragma unroll
  for (int c = 0; c < 32; ++c) acc[c] = *(const f32x4*)(b2 + 4 * c);

  for (int k4 = 0; k4 < 32; ++k4) {
    const f32x4 h = *(const f32x4*)(h1 + row + 4 * k4);
#pragma unroll
    for (int kk = 0; kk < 4; ++kk) {
      const float hk = h[kk];
      const float* wr = u2 + (size_t)(4 * k4 + kk) * 128;
#pragma unroll
      for (int c = 0; c < 32; ++c) acc[c] += hk * *(const f32x4*)(wr + 4 * c);
    }
  }

  if (act) {
    float s = 0.f, s2 = 0.f;
#pragma unroll
    for (int c = 0; c < 32; ++c) {
      const f32x4 nd = *(const f32x4*)(node_state + row + 4 * c);
      f32x4 x = nd + acc[c];
      acc[c] = x;
#pragma unroll
      for (int i = 0; i < 4; ++i) { s += x[i]; s2 += x[i] * x[i]; }
    }
    const float mu = s * (1.0f / 128.0f);
    float var = s2 * (1.0f / 128.0f) - mu * mu;
    var = var < 0.f ? 0.f : var;
    const float rstd = rsqrtf(var + 1e-5f);
    float* o = out + (size_t)n * 128;
#pragma unroll
    for (int c = 0; c < 32; ++c) {
      const f32x4 g = *(const f32x4*)(lng + 4 * c);
      const f32x4 b = *(const f32x4*)(lnb + 4 * c);
      f32x4 x = acc[c];
#pragma unroll
      for (int i = 0; i < 4; ++i) x[i] = (x[i] - mu) * rstd * g[i] + b[i];
      *(f32x4*)(o + 4 * c) = x;
    }
  }
}

// ---------------------------------------------------------------------------
extern "C" void kernel_launch(void* const* d_in, const int* in_sizes, int n_in,
                              void* d_out, int out_size, void* d_ws, size_t ws_size,
                              hipStream_t stream)
{
  const float* node_state = (const float*)d_in[0];
  const int* ei           = (const int*)d_in[1];   // int64 in reference -> int32 from harness
  const float* edge_state = (const float*)d_in[2];
  const float* gstate     = (const float*)d_in[3];
  const float* msg_w1     = (const float*)d_in[4];
  const float* msg_b1     = (const float*)d_in[5];
  const float* msg_w2     = (const float*)d_in[6];
  const float* msg_b2     = (const float*)d_in[7];
  const float* upd_w1     = (const float*)d_in[8];
  const float* upd_b1     = (const float*)d_in[9];
  const float* upd_w2     = (const float*)d_in[10];
  const float* upd_b2     = (const float*)d_in[11];
  const float* ln_g       = (const float*)d_in[12];
  const float* ln_b       = (const float*)d_in[13];

  char* ws = (char*)d_ws;
  float* agg              = (float*)(ws + 0);                  // 51,200,000 B
  int* cnt                = (int*)(ws + 51200000);             //    400,000 B
  // h1buf region (51.2 MB) double-books the CSR scratch: CSR arrays are dead
  // before upd1 writes h1.
  float* h1buf            = (float*)(ws + 51600000);           // 51,200,000 B
  int* csr                = (int*)(ws + 51600000);             //  6,400,000 B
  int* row_start          = (int*)(ws + 58000000);             //    400,000 B
  int* cursor             = (int*)(ws + 58400000);             //    400,000 B
  unsigned short* w1b     = (unsigned short*)(ws + 102800000); //     65,536 B
  unsigned short* w2b     = (unsigned short*)(ws + 102865536); //     32,768 B
  unsigned short* gb      = (unsigned short*)(ws + 102898304); //        128 B
  (void)ws_size; (void)in_sizes; (void)n_in; (void)out_size;

  hipMemsetAsync(ws, 0, 51600000, stream);  // agg + cnt
  hipLaunchKernelGGL(convert_kernel, dim3(128), dim3(256), 0, stream,
                     msg_w1, msg_w2, gstate, w1b, w2b, gb);
  hipLaunchKernelGGL(hist_kernel, dim3(2048), dim3(256), 0, stream, ei, cnt);
  hipLaunchKernelGGL(scan_kernel, dim3(1), dim3(1024), 0, stream, cnt, row_start, cursor);
  hipLaunchKernelGGL(scatter_kernel, dim3(2048), dim3(256), 0, stream, ei, cursor, csr);
  hipLaunchKernelGGL(edge_kernel, dim3(768), dim3(256), 0, stream,
                     ei, edge_state, node_state, csr, w1b, w2b, msg_b1, msg_b2, gb, agg);
  hipLaunchKernelGGL(upd1_kernel, dim3((NN + 127) / 128), dim3(128), 0, stream,
                     node_state, agg, cnt, upd_w1, upd_b1, gstate, h1buf);
  hipLaunchKernelGGL(upd2_kernel, dim3((NN + 127) / 128), dim3(128), 0, stream,
                     node_state, h1buf, upd_w2, upd_b2, ln_g, ln_b, (float*)d_out);
}

// Round 5
// 1478.468 us; speedup vs baseline: 1.6163x; 1.6163x over previous
//
#include <hip/hip_runtime.h>
#include <hip/hip_bf16.h>
#include <stdint.h>

#define NN 100000
#define NE 1600000
#define NB 391  // ceil(NN/256)

typedef __attribute__((ext_vector_type(4))) float f32x4;
typedef __attribute__((ext_vector_type(2))) float f32x2;
typedef __attribute__((ext_vector_type(8))) __bf16 bf16x8;
typedef __attribute__((ext_vector_type(8))) short s16x8;
typedef __attribute__((ext_vector_type(4))) unsigned int u32x4;
typedef __attribute__((ext_vector_type(2))) unsigned int u32x2;

__device__ __forceinline__ unsigned short f2bf(float f) {
  unsigned int u = __builtin_bit_cast(unsigned int, f);
  u += 0x7fffu + ((u >> 16) & 1u);
  return (unsigned short)(u >> 16);
}

__device__ __forceinline__ f32x4 mfma16(bf16x8 a, bf16x8 b, f32x4 c) {
  return __builtin_amdgcn_mfma_f32_16x16x32_bf16(a, b, c, 0, 0, 0);
}

// ---------------------------------------------------------------------------
// setup: convert msg weights + global to bf16 (edge kernel only)
// ---------------------------------------------------------------------------
__global__ void convert_kernel(const float* __restrict__ w1, const float* __restrict__ w2,
                               const float* __restrict__ g,
                               unsigned short* __restrict__ w1b, unsigned short* __restrict__ w2b,
                               unsigned short* __restrict__ gb)
{
  const int tid = blockIdx.x * 256 + threadIdx.x;
  if (tid < 256 * 128) w1b[tid] = f2bf(w1[tid]);
  if (tid < 128 * 128) w2b[tid] = f2bf(w2[tid]);
  if (tid < 64) gb[tid] = f2bf(g[tid]);
}

// ---------------------------------------------------------------------------
// CSR-lite build: hist -> coalesced 3-kernel scan -> scatter (epos only)
// ---------------------------------------------------------------------------
__global__ void hist_kernel(const int* __restrict__ ei, int* __restrict__ cnt)
{
  int i = blockIdx.x * 256 + threadIdx.x;
  const int stride = gridDim.x * 256;
  for (; i < NE; i += stride) atomicAdd(&cnt[ei[NE + i]], 1);
}

__global__ void scanA_kernel(const int* __restrict__ cnt, int* __restrict__ bsum)
{
  __shared__ int s[256];
  const int t = threadIdx.x;
  const int idx = blockIdx.x * 256 + t;
  s[t] = idx < NN ? cnt[idx] : 0;
  __syncthreads();
  for (int off = 128; off > 0; off >>= 1) {
    if (t < off) s[t] += s[t + off];
    __syncthreads();
  }
  if (t == 0) bsum[blockIdx.x] = s[0];
}

__global__ __launch_bounds__(512) void scanB_kernel(const int* __restrict__ bsum,
                                                    int* __restrict__ boff)
{
  __shared__ int s[512];
  const int t = threadIdx.x;
  const int v = t < NB ? bsum[t] : 0;
  s[t] = v;
  __syncthreads();
  for (int off = 1; off < 512; off <<= 1) {
    const int x = t >= off ? s[t - off] : 0;
    __syncthreads();
    s[t] += x;
    __syncthreads();
  }
  if (t < NB) boff[t] = s[t] - v;  // exclusive
}

__global__ void scanC_kernel(const int* __restrict__ cnt, const int* __restrict__ boff,
                             int* __restrict__ row_start, int* __restrict__ cursor)
{
  __shared__ int s[256];
  const int t = threadIdx.x;
  const int idx = blockIdx.x * 256 + t;
  const int v = idx < NN ? cnt[idx] : 0;
  s[t] = v;
  __syncthreads();
  for (int off = 1; off < 256; off <<= 1) {
    const int x = t >= off ? s[t - off] : 0;
    __syncthreads();
    s[t] += x;
    __syncthreads();
  }
  const int ex = s[t] - v + boff[blockIdx.x];
  if (idx < NN) { row_start[idx] = ex; cursor[idx] = ex; }
}

__global__ void scatter_kernel(const int* __restrict__ ei, int* __restrict__ cursor,
                               int* __restrict__ epos)
{
  int i = blockIdx.x * 256 + threadIdx.x;
  const int stride = gridDim.x * 256;
  for (; i < NE; i += stride) {
    const int d = ei[NE + i];
    epos[i] = atomicAdd(&cursor[d], 1);
  }
}

// ---------------------------------------------------------------------------
// edge msg kernel (ORIGINAL edge order -> sequential edge_state stream):
// msg = MLP(concat(node[src], edge_state, gs)) in bf16 MFMA;
// row written as fp8-e4m3 (128 B) to dst-sorted slot msg[epos[e]].
// ---------------------------------------------------------------------------
__global__ __launch_bounds__(256, 3) void edge_msg_kernel(
    const int* __restrict__ ei,
    const float* __restrict__ edge_state,
    const float* __restrict__ node_state,
    const int* __restrict__ epos,
    const unsigned short* __restrict__ w1b,
    const unsigned short* __restrict__ w2b,
    const float* __restrict__ bias1g,
    const float* __restrict__ bias2g,
    const unsigned short* __restrict__ gb,
    unsigned int* __restrict__ msg)   // [NE][32] u32 (128 fp8 per row)
{
  __shared__ unsigned short sX[64 * 256];  // 32 KB staging; front 16 KB reused as msg bf16 tile
  __shared__ unsigned short sH[64 * 128];  // 16 KB h1
  __shared__ int sPos[64];

  const int t = threadIdx.x;
  const int lane = t & 63;
  const int wv = t >> 6;
  const int l15 = lane & 15;
  const int lq = lane >> 4;

  // preload W1/W2 B-fragments into registers (per-wave column slice)
  bf16x8 b1f[8][2], b2f[4][2];
  float bs1[2], bs2[2];
  for (int n = 0; n < 2; ++n) {
    const int col = wv * 32 + n * 16 + l15;
    bs1[n] = bias1g[col];
    bs2[n] = bias2g[col];
    for (int ks = 0; ks < 8; ++ks) {
      const int k0 = ks * 32 + lq * 8;
      s16x8 v;
#pragma unroll
      for (int j = 0; j < 8; ++j) v[j] = (short)w1b[(k0 + j) * 128 + col];
      b1f[ks][n] = __builtin_bit_cast(bf16x8, v);
    }
    for (int ks = 0; ks < 4; ++ks) {
      const int k0 = ks * 32 + lq * 8;
      s16x8 v;
#pragma unroll
      for (int j = 0; j < 8; ++j) v[j] = (short)w2b[(k0 + j) * 128 + col];
      b2f[ks][n] = __builtin_bit_cast(bf16x8, v);
    }
  }

  const int r = t >> 2;   // edge row within tile
  const int p = t & 3;    // quarter of the row
  const int rs = r & 7;   // swizzle key

  for (int tile = blockIdx.x; tile < NE / 64; tile += gridDim.x) {
    __syncthreads();  // prior iteration's out-store reads sX
    const int e0 = tile * 64;

    // ---- stage ----
    const int e = e0 + r;
    const int src = ei[e];
    if (p == 0) sPos[r] = epos[e];
    {  // node gather (f32 -> bf16): chunks 0..15
      const f32x4* nsv = (const f32x4*)(node_state + (size_t)src * 128 + p * 32);
#pragma unroll
      for (int j = 0; j < 4; ++j) {
        f32x4 x0 = nsv[2 * j], x1 = nsv[2 * j + 1];
        unsigned short buf[8];
#pragma unroll
        for (int i = 0; i < 4; ++i) { buf[i] = f2bf(x0[i]); buf[4 + i] = f2bf(x1[i]); }
        const int c = p * 4 + j;
        *(u32x4*)((char*)sX + r * 512 + ((c ^ rs) * 16)) = *(u32x4*)buf;
      }
    }
    {  // edge_state (sequential stream): f32 -> bf16, chunks 16..23
      const f32x4* es = (const f32x4*)(edge_state + (size_t)e * 64 + p * 16);
      f32x4 e0v = es[0], e1v = es[1], e2v = es[2], e3v = es[3];
      unsigned short bufa[8], bufb[8];
#pragma unroll
      for (int i = 0; i < 4; ++i) {
        bufa[i] = f2bf(e0v[i]); bufa[4 + i] = f2bf(e1v[i]);
        bufb[i] = f2bf(e2v[i]); bufb[4 + i] = f2bf(e3v[i]);
      }
      const int c = 16 + 2 * p;
      *(u32x4*)((char*)sX + r * 512 + ((c ^ rs) * 16)) = *(u32x4*)bufa;
      *(u32x4*)((char*)sX + r * 512 + (((c + 1) ^ rs) * 16)) = *(u32x4*)bufb;
    }
    {  // global (pre-converted bf16): chunks 24..31
      const u32x4* g = (const u32x4*)(gb + p * 16);
      const int c = 24 + 2 * p;
      *(u32x4*)((char*)sX + r * 512 + ((c ^ rs) * 16)) = g[0];
      *(u32x4*)((char*)sX + r * 512 + (((c + 1) ^ rs) * 16)) = g[1];
    }
    __syncthreads();

    // ---- phase 1: h1 = relu(X @ W1 + b1) ----
    f32x4 acc[4][2];
#pragma unroll
    for (int m = 0; m < 4; ++m)
#pragma unroll
      for (int n = 0; n < 2; ++n)
        acc[m][n] = (f32x4){bs1[n], bs1[n], bs1[n], bs1[n]};
#pragma unroll
    for (int ks = 0; ks < 8; ++ks) {
      bf16x8 a[4];
#pragma unroll
      for (int m = 0; m < 4; ++m) {
        const int row = m * 16 + l15;
        a[m] = *(const bf16x8*)((const char*)sX + row * 512 + (((4 * ks + lq) ^ (row & 7)) * 16));
      }
#pragma unroll
      for (int m = 0; m < 4; ++m)
#pragma unroll
        for (int n = 0; n < 2; ++n)
          acc[m][n] = mfma16(a[m], b1f[ks][n], acc[m][n]);
    }
    // relu + store h1 (swizzled bf16 [64][128])
#pragma unroll
    for (int m = 0; m < 4; ++m)
#pragma unroll
      for (int n = 0; n < 2; ++n)
#pragma unroll
        for (int i = 0; i < 4; ++i) {
          const int row = m * 16 + lq * 4 + i;
          const int col = wv * 32 + n * 16 + l15;
          float v = acc[m][n][i];
          v = v > 0.f ? v : 0.f;
          *(unsigned short*)((char*)sH + row * 256 +
                             ((((col >> 3) ^ (row & 7)) * 16) + (col & 7) * 2)) = f2bf(v);
        }
    __syncthreads();  // h1 ready; sX phase-1 reads done

    // ---- phase 2: msg = h1 @ W2 + b2 -> bf16 tile in sX front (swizzled) ----
    f32x4 acc2[4][2];
#pragma unroll
    for (int m = 0; m < 4; ++m)
#pragma unroll
      for (int n = 0; n < 2; ++n)
        acc2[m][n] = (f32x4){bs2[n], bs2[n], bs2[n], bs2[n]};
#pragma unroll
    for (int ks = 0; ks < 4; ++ks) {
      bf16x8 a[4];
#pragma unroll
      for (int m = 0; m < 4; ++m) {
        const int row = m * 16 + l15;
        a[m] = *(const bf16x8*)((const char*)sH + row * 256 + (((4 * ks + lq) ^ (row & 7)) * 16));
      }
#pragma unroll
      for (int m = 0; m < 4; ++m)
#pragma unroll
        for (int n = 0; n < 2; ++n)
          acc2[m][n] = mfma16(a[m], b2f[ks][n], acc2[m][n]);
    }
#pragma unroll
    for (int m = 0; m < 4; ++m)
#pragma unroll
      for (int n = 0; n < 2; ++n)
#pragma unroll
        for (int i = 0; i < 4; ++i) {
          const int row = m * 16 + lq * 4 + i;
          const int col = wv * 32 + n * 16 + l15;
          *(unsigned short*)((char*)sX + row * 256 +
                             ((((col >> 3) ^ (row & 7)) * 16) + (col & 7) * 2)) = f2bf(acc2[m][n][i]);
        }
    __syncthreads();

    // ---- out-store: row r quarter p -> fp8 at dst-sorted slot ----
    {
      const int pos = sPos[r];
      unsigned int* mrow = msg + (size_t)pos * 32;
#pragma unroll
      for (int cc = 4 * p; cc < 4 * p + 4; ++cc) {
        const u32x4 ch = *(const u32x4*)((const char*)sX + r * 256 + ((cc ^ rs) * 16));
        unsigned int w0 = 0, w1 = 0;
        float f[8];
#pragma unroll
        for (int q = 0; q < 4; ++q) {
          f[2 * q]     = __builtin_bit_cast(float, ch[q] << 16);
          f[2 * q + 1] = __builtin_bit_cast(float, ch[q] & 0xffff0000u);
        }
        w0 = __builtin_amdgcn_cvt_pk_fp8_f32(f[0], f[1], 0, false);
        w0 = __builtin_amdgcn_cvt_pk_fp8_f32(f[2], f[3], w0, true);
        w1 = __builtin_amdgcn_cvt_pk_fp8_f32(f[4], f[5], 0, false);
        w1 = __builtin_amdgcn_cvt_pk_fp8_f32(f[6], f[7], w1, true);
        *(u32x2*)(mrow + cc * 2) = (u32x2){(unsigned int)w0, (unsigned int)w1};
      }
    }
  }
}

// ---------------------------------------------------------------------------
// aggregate: sequential segmented sum over dst-sorted fp8 msg -> f32 agg
// wave handles node pairs: lanes 0-31 node A, lanes 32-63 node B (4 cols/lane)
// ---------------------------------------------------------------------------
__global__ __launch_bounds__(256) void agg_kernel(
    const unsigned int* __restrict__ msg,
    const int* __restrict__ row_start,
    const int* __restrict__ cnt,
    float* __restrict__ agg)
{
  const int t = threadIdx.x;
  const int wv = t >> 6;
  const int lane = t & 63;
  const int half = lane >> 5;
  const int l32 = lane & 31;
  const int base = blockIdx.x * 64 + wv * 16;

  for (int k = 0; k < 8; ++k) {
    const int n = base + 2 * k + half;
    const bool act = n < NN;
    const int s = act ? row_start[n] : 0;
    const int c = act ? cnt[n] : 0;
    f32x4 acc = (f32x4){0.f, 0.f, 0.f, 0.f};
    for (int j = 0; j < c; ++j) {
      const int w = (int)msg[(size_t)(s + j) * 32 + l32];
      const f32x2 lo = __builtin_amdgcn_cvt_pk_f32_fp8(w, false);
      const f32x2 hi = __builtin_amdgcn_cvt_pk_f32_fp8(w, true);
      acc[0] += lo[0]; acc[1] += lo[1]; acc[2] += hi[0]; acc[3] += hi[1];
    }
    if (act) *(f32x4*)(agg + (size_t)n * 128 + l32 * 4) = acc;
  }
}

// ---------------------------------------------------------------------------
// update MLP phase 1 in full f32 (VALU): h1 = relu(X @ U1 + b1), K = 320
// ---------------------------------------------------------------------------
__global__ __launch_bounds__(128, 3) void upd1_kernel(
    const float* __restrict__ node_state,
    const float* __restrict__ agg,
    const int* __restrict__ cnt,
    const float* __restrict__ u1,    // [320][128] f32
    const float* __restrict__ b1,
    const float* __restrict__ gs,    // [64] f32
    float* __restrict__ h1out)
{
  const int n = blockIdx.x * 128 + threadIdx.x;
  const bool act = n < NN;
  const size_t row = (size_t)(act ? n : 0) * 128;

  f32x4 acc[32];
#pragma unroll
  for (int c = 0; c < 32; ++c) acc[c] = *(const f32x4*)(b1 + 4 * c);

  const float rdeg = act ? (1.0f / (float)max(cnt[n], 1)) : 0.0f;

  for (int k4 = 0; k4 < 32; ++k4) {
    const f32x4 x = *(const f32x4*)(node_state + row + 4 * k4);
#pragma unroll
    for (int kk = 0; kk < 4; ++kk) {
      const float xk = x[kk];
      const float* wr = u1 + (size_t)(4 * k4 + kk) * 128;
#pragma unroll
      for (int c = 0; c < 32; ++c) acc[c] += xk * *(const f32x4*)(wr + 4 * c);
    }
  }
  for (int k4 = 0; k4 < 32; ++k4) {
    const f32x4 x = *(const f32x4*)(agg + row + 4 * k4);
#pragma unroll
    for (int kk = 0; kk < 4; ++kk) {
      const float xk = x[kk] * rdeg;
      const float* wr = u1 + (size_t)(128 + 4 * k4 + kk) * 128;
#pragma unroll
      for (int c = 0; c < 32; ++c) acc[c] += xk * *(const f32x4*)(wr + 4 * c);
    }
  }
  for (int k = 0; k < 64; ++k) {
    const float xk = gs[k];
    const float* wr = u1 + (size_t)(256 + k) * 128;
#pragma unroll
    for (int c = 0; c < 32; ++c) acc[c] += xk * *(const f32x4*)(wr + 4 * c);
  }

  if (act) {
    float* o = h1out + (size_t)n * 128;
#pragma unroll
    for (int c = 0; c < 32; ++c) {
      f32x4 v = acc[c];
#pragma unroll
      for (int i = 0; i < 4; ++i) v[i] = v[i] > 0.f ? v[i] : 0.f;
      *(f32x4*)(o + 4 * c) = v;
    }
  }
}

// ---------------------------------------------------------------------------
// update MLP phase 2 + residual + LayerNorm, full f32 (VALU)
// ---------------------------------------------------------------------------
__global__ __launch_bounds__(128, 3) void upd2_kernel(
    const float* __restrict__ node_state,
    const float* __restrict__ h1,
    const float* __restrict__ u2,    // [128][128] f32
    const float* __restrict__ b2,
    const float* __restrict__ lng,
    const float* __restrict__ lnb,
    float* __restrict__ out)
{
  const int n = blockIdx.x * 128 + threadIdx.x;
  const bool act = n < NN;
  const size_t row = (size_t)(act ? n : 0) * 128;

  f32x4 acc[32];
#pragma unroll
  for (int c = 0; c < 32; ++c) acc[c] = *(const f32x4*)(b2 + 4 * c);

  for (int k4 = 0; k4 < 32; ++k4) {
    const f32x4 h = *(const f32x4*)(h1 + row + 4 * k4);
#pragma unroll
    for (int kk = 0; kk < 4; ++kk) {
      const float hk = h[kk];
      const float* wr = u2 + (size_t)(4 * k4 + kk) * 128;
#pragma unroll
      for (int c = 0; c < 32; ++c) acc[c] += hk * *(const f32x4*)(wr + 4 * c);
    }
  }

  if (act) {
    float s = 0.f, s2 = 0.f;
#pragma unroll
    for (int c = 0; c < 32; ++c) {
      const f32x4 nd = *(const f32x4*)(node_state + row + 4 * c);
      f32x4 x = nd + acc[c];
      acc[c] = x;
#pragma unroll
      for (int i = 0; i < 4; ++i) { s += x[i]; s2 += x[i] * x[i]; }
    }
    const float mu = s * (1.0f / 128.0f);
    float var = s2 * (1.0f / 128.0f) - mu * mu;
    var = var < 0.f ? 0.f : var;
    const float rstd = rsqrtf(var + 1e-5f);
    float* o = out + (size_t)n * 128;
#pragma unroll
    for (int c = 0; c < 32; ++c) {
      const f32x4 g = *(const f32x4*)(lng + 4 * c);
      const f32x4 b = *(const f32x4*)(lnb + 4 * c);
      f32x4 x = acc[c];
#pragma unroll
      for (int i = 0; i < 4; ++i) x[i] = (x[i] - mu) * rstd * g[i] + b[i];
      *(f32x4*)(o + 4 * c) = x;
    }
  }
}

// ---------------------------------------------------------------------------
extern "C" void kernel_launch(void* const* d_in, const int* in_sizes, int n_in,
                              void* d_out, int out_size, void* d_ws, size_t ws_size,
                              hipStream_t stream)
{
  const float* node_state = (const float*)d_in[0];
  const int* ei           = (const int*)d_in[1];   // int64 in reference -> int32 from harness
  const float* edge_state = (const float*)d_in[2];
  const float* gstate     = (const float*)d_in[3];
  const float* msg_w1     = (const float*)d_in[4];
  const float* msg_b1     = (const float*)d_in[5];
  const float* msg_w2     = (const float*)d_in[6];
  const float* msg_b2     = (const float*)d_in[7];
  const float* upd_w1     = (const float*)d_in[8];
  const float* upd_b1     = (const float*)d_in[9];
  const float* upd_w2     = (const float*)d_in[10];
  const float* upd_b2     = (const float*)d_in[11];
  const float* ln_g       = (const float*)d_in[12];
  const float* ln_b       = (const float*)d_in[13];

  char* ws = (char*)d_ws;
  float* agg              = (float*)(ws + 0);                  // 51,200,000
  int* cnt                = (int*)(ws + 51200000);             //    400,000
  int* row_start          = (int*)(ws + 51600000);             //    400,000
  int* cursor             = (int*)(ws + 52000000);             //    400,000
  int* bsum               = (int*)(ws + 52400000);             //      1,564 (pad)
  int* boff               = (int*)(ws + 52404096);             //      1,564 (pad)
  int* epos               = (int*)(ws + 52408192);             //  6,400,000
  unsigned short* w1b     = (unsigned short*)(ws + 58808192);  //     65,536
  unsigned short* w2b     = (unsigned short*)(ws + 58873728);  //     32,768
  unsigned short* gb      = (unsigned short*)(ws + 58906496);  //        128
  unsigned int* msgbuf    = (unsigned int*)(ws + 58906624);    // 204,800,000 (fp8 [NE][128])
  float* h1buf            = (float*)(ws + 58906624);           // aliases msgbuf (dead by upd1)
  (void)ws_size; (void)in_sizes; (void)n_in; (void)out_size;

  hipMemsetAsync(cnt, 0, 400000, stream);
  hipLaunchKernelGGL(convert_kernel, dim3(128), dim3(256), 0, stream,
                     msg_w1, msg_w2, gstate, w1b, w2b, gb);
  hipLaunchKernelGGL(hist_kernel, dim3(2048), dim3(256), 0, stream, ei, cnt);
  hipLaunchKernelGGL(scanA_kernel, dim3(NB), dim3(256), 0, stream, cnt, bsum);
  hipLaunchKernelGGL(scanB_kernel, dim3(1), dim3(512), 0, stream, bsum, boff);
  hipLaunchKernelGGL(scanC_kernel, dim3(NB), dim3(256), 0, stream, cnt, boff, row_start, cursor);
  hipLaunchKernelGGL(scatter_kernel, dim3(2048), dim3(256), 0, stream, ei, cursor, epos);
  hipLaunchKernelGGL(edge_msg_kernel, dim3(768), dim3(256), 0, stream,
                     ei, edge_state, node_state, epos, w1b, w2b, msg_b1, msg_b2, gb, msgbuf);
  hipLaunchKernelGGL(agg_kernel, dim3((NN + 63) / 64), dim3(256), 0, stream,
                     msgbuf, row_start, cnt, agg);
  hipLaunchKernelGGL(upd1_kernel, dim3((NN + 127) / 128), dim3(128), 0, stream,
                     node_state, agg, cnt, upd_w1, upd_b1, gstate, h1buf);
  hipLaunchKernelGGL(upd2_kernel, dim3((NN + 127) / 128), dim3(128), 0, stream,
                     node_state, h1buf, upd_w2, upd_b2, ln_g, ln_b, (float*)d_out);
}

// Round 6
// 1445.126 us; speedup vs baseline: 1.6536x; 1.0231x over previous
//
#include <hip/hip_runtime.h>
#include <hip/hip_bf16.h>
#include <stdint.h>

#define NN 100000
#define NE 1600000
#define NB 391     // ceil(NN/256)
#define NT 25000   // NE/64

typedef __attribute__((ext_vector_type(4))) float f32x4;
typedef __attribute__((ext_vector_type(2))) float f32x2;
typedef __attribute__((ext_vector_type(8))) __bf16 bf16x8;
typedef __attribute__((ext_vector_type(8))) short s16x8;
typedef __attribute__((ext_vector_type(4))) unsigned int u32x4;
typedef __attribute__((ext_vector_type(2))) unsigned int u32x2;

__device__ __forceinline__ unsigned short f2bf(float f) {
  unsigned int u = __builtin_bit_cast(unsigned int, f);
  u += 0x7fffu + ((u >> 16) & 1u);
  return (unsigned short)(u >> 16);
}

__device__ __forceinline__ f32x4 mfma16(bf16x8 a, bf16x8 b, f32x4 c) {
  return __builtin_amdgcn_mfma_f32_16x16x32_bf16(a, b, c, 0, 0, 0);
}

// ---------------------------------------------------------------------------
// setup: node_state -> bf16 table; msg weights + global -> bf16
// ---------------------------------------------------------------------------
__global__ void convert_kernel(const float* __restrict__ ns,
                               const float* __restrict__ w1, const float* __restrict__ w2,
                               const float* __restrict__ g,
                               unsigned short* __restrict__ node_bf,
                               unsigned short* __restrict__ w1b, unsigned short* __restrict__ w2b,
                               unsigned short* __restrict__ gb)
{
  const int tid = blockIdx.x * 256 + threadIdx.x;
  const int stride = gridDim.x * 256;
  for (int i = tid; i < NN * 128; i += stride) node_bf[i] = f2bf(ns[i]);
  if (tid < 256 * 128) w1b[tid] = f2bf(w1[tid]);
  if (tid < 128 * 128) w2b[tid] = f2bf(w2[tid]);
  if (tid < 64) gb[tid] = f2bf(g[tid]);
}

// ---------------------------------------------------------------------------
// CSR-lite build: hist -> coalesced 3-kernel scan -> scatter (epos only)
// ---------------------------------------------------------------------------
__global__ void hist_kernel(const int* __restrict__ ei, int* __restrict__ cnt)
{
  int i = blockIdx.x * 256 + threadIdx.x;
  const int stride = gridDim.x * 256;
  for (; i < NE; i += stride) atomicAdd(&cnt[ei[NE + i]], 1);
}

__global__ void scanA_kernel(const int* __restrict__ cnt, int* __restrict__ bsum)
{
  __shared__ int s[256];
  const int t = threadIdx.x;
  const int idx = blockIdx.x * 256 + t;
  s[t] = idx < NN ? cnt[idx] : 0;
  __syncthreads();
  for (int off = 128; off > 0; off >>= 1) {
    if (t < off) s[t] += s[t + off];
    __syncthreads();
  }
  if (t == 0) bsum[blockIdx.x] = s[0];
}

__global__ __launch_bounds__(512) void scanB_kernel(const int* __restrict__ bsum,
                                                    int* __restrict__ boff)
{
  __shared__ int s[512];
  const int t = threadIdx.x;
  const int v = t < NB ? bsum[t] : 0;
  s[t] = v;
  __syncthreads();
  for (int off = 1; off < 512; off <<= 1) {
    const int x = t >= off ? s[t - off] : 0;
    __syncthreads();
    s[t] += x;
    __syncthreads();
  }
  if (t < NB) boff[t] = s[t] - v;  // exclusive
}

__global__ void scanC_kernel(const int* __restrict__ cnt, const int* __restrict__ boff,
                             int* __restrict__ row_start, int* __restrict__ cursor)
{
  __shared__ int s[256];
  const int t = threadIdx.x;
  const int idx = blockIdx.x * 256 + t;
  const int v = idx < NN ? cnt[idx] : 0;
  s[t] = v;
  __syncthreads();
  for (int off = 1; off < 256; off <<= 1) {
    const int x = t >= off ? s[t - off] : 0;
    __syncthreads();
    s[t] += x;
    __syncthreads();
  }
  const int ex = s[t] - v + boff[blockIdx.x];
  if (idx < NN) { row_start[idx] = ex; cursor[idx] = ex; }
}

__global__ void scatter_kernel(const int* __restrict__ ei, int* __restrict__ cursor,
                               int* __restrict__ epos)
{
  int i = blockIdx.x * 256 + threadIdx.x;
  const int stride = gridDim.x * 256;
  for (; i < NE; i += stride) {
    const int d = ei[NE + i];
    epos[i] = atomicAdd(&cursor[d], 1);
  }
}

// ---------------------------------------------------------------------------
// edge msg kernel (original edge order, register-prefetch double-buffered):
// msg = MLP(concat(node_bf[src], edge_state, gs)) in bf16 MFMA;
// row written as fp8-e4m3 (128 B) to dst-sorted slot msg[epos[e]].
// Tile t's gathers are issued during tile t-1's MFMA phases (T14).
// ---------------------------------------------------------------------------
__global__ __launch_bounds__(256, 3) void edge_msg_kernel(
    const int* __restrict__ ei,
    const float* __restrict__ edge_state,
    const unsigned short* __restrict__ node_bf,
    const int* __restrict__ epos,
    const unsigned short* __restrict__ w1b,
    const unsigned short* __restrict__ w2b,
    const float* __restrict__ bias1g,
    const float* __restrict__ bias2g,
    const unsigned short* __restrict__ gb,
    unsigned int* __restrict__ msg)   // [NE][32] u32 (128 fp8 per row)
{
  __shared__ unsigned short sX[64 * 256];  // 32 KB staging; front 16 KB reused as msg bf16 tile
  __shared__ unsigned short sH[64 * 128];  // 16 KB h1
  __shared__ int sPos[64];

  const int t = threadIdx.x;
  const int lane = t & 63;
  const int wv = t >> 6;
  const int l15 = lane & 15;
  const int lq = lane >> 4;

  // preload W1/W2 B-fragments into registers (per-wave column slice)
  bf16x8 b1f[8][2], b2f[4][2];
  float bs1[2], bs2[2];
  for (int n = 0; n < 2; ++n) {
    const int col = wv * 32 + n * 16 + l15;
    bs1[n] = bias1g[col];
    bs2[n] = bias2g[col];
    for (int ks = 0; ks < 8; ++ks) {
      const int k0 = ks * 32 + lq * 8;
      s16x8 v;
#pragma unroll
      for (int j = 0; j < 8; ++j) v[j] = (short)w1b[(k0 + j) * 128 + col];
      b1f[ks][n] = __builtin_bit_cast(bf16x8, v);
    }
    for (int ks = 0; ks < 4; ++ks) {
      const int k0 = ks * 32 + lq * 8;
      s16x8 v;
#pragma unroll
      for (int j = 0; j < 8; ++j) v[j] = (short)w2b[(k0 + j) * 128 + col];
      b2f[ks][n] = __builtin_bit_cast(bf16x8, v);
    }
  }

  const int r = t >> 2;   // edge row within tile
  const int p = t & 3;    // quarter of the row
  const int rs = r & 7;   // swizzle key

  // global-state chunks are constant: preload once
  u32x4 gR0, gR1;
  {
    const u32x4* g = (const u32x4*)(gb + p * 16);
    gR0 = g[0]; gR1 = g[1];
  }

  const int grid = gridDim.x;

  // ---- prologue: gather tile0 data; load indices for tile1 ----
  u32x4 pfN[4];
  f32x4 pfE[4];
  int srcNext, posNext, posCur;
  {
    const int e0 = blockIdx.x * 64 + r;
    const int s0 = ei[e0];
    posCur = epos[e0];
    const u32x4* nb = (const u32x4*)(node_bf + (size_t)s0 * 128);
    const f32x4* es = (const f32x4*)(edge_state + (size_t)e0 * 64);
#pragma unroll
    for (int j = 0; j < 4; ++j) { pfN[j] = nb[p * 4 + j]; pfE[j] = es[p * 4 + j]; }
    const int t1 = blockIdx.x + grid;
    const int e1 = min(t1 * 64 + r, NE - 1);
    srcNext = ei[e1];
    posNext = epos[e1];
  }

  for (int tile = blockIdx.x; tile < NT; tile += grid) {
    __syncthreads();  // prior iteration's out-store done reading sX front

    // ---- stage: pure reg -> LDS ----
    if (p == 0) sPos[r] = posCur;
#pragma unroll
    for (int j = 0; j < 4; ++j) {   // node chunks 0..15
      const int c = p * 4 + j;
      *(u32x4*)((char*)sX + r * 512 + ((c ^ rs) * 16)) = pfN[j];
    }
    {  // edge chunks 16..23 (f32 -> bf16)
      unsigned short bufa[8], bufb[8];
#pragma unroll
      for (int i = 0; i < 4; ++i) {
        bufa[i] = f2bf(pfE[0][i]); bufa[4 + i] = f2bf(pfE[1][i]);
        bufb[i] = f2bf(pfE[2][i]); bufb[4 + i] = f2bf(pfE[3][i]);
      }
      const int c = 16 + 2 * p;
      *(u32x4*)((char*)sX + r * 512 + ((c ^ rs) * 16)) = *(u32x4*)bufa;
      *(u32x4*)((char*)sX + r * 512 + (((c + 1) ^ rs) * 16)) = *(u32x4*)bufb;
    }
    {  // global chunks 24..31 (from regs; front rows get clobbered each iter)
      const int c = 24 + 2 * p;
      *(u32x4*)((char*)sX + r * 512 + ((c ^ rs) * 16)) = gR0;
      *(u32x4*)((char*)sX + r * 512 + (((c + 1) ^ rs) * 16)) = gR1;
    }
    __syncthreads();

    // ---- issue next tile's gathers + indices (latency hidden by MFMA) ----
    {
      const int tn = tile + grid;
      const int eN = min(tn * 64 + r, NE - 1);
      const u32x4* nb = (const u32x4*)(node_bf + (size_t)srcNext * 128);
      const f32x4* es = (const f32x4*)(edge_state + (size_t)eN * 64);
#pragma unroll
      for (int j = 0; j < 4; ++j) { pfN[j] = nb[p * 4 + j]; pfE[j] = es[p * 4 + j]; }
      posCur = posNext;
      const int e2 = min((tn + grid) * 64 + r, NE - 1);
      srcNext = ei[e2];
      posNext = epos[e2];
    }

    // ---- phase 1: h1 = relu(X @ W1 + b1) ----
    f32x4 acc[4][2];
#pragma unroll
    for (int m = 0; m < 4; ++m)
#pragma unroll
      for (int n = 0; n < 2; ++n)
        acc[m][n] = (f32x4){bs1[n], bs1[n], bs1[n], bs1[n]};
#pragma unroll
    for (int ks = 0; ks < 8; ++ks) {
      bf16x8 a[4];
#pragma unroll
      for (int m = 0; m < 4; ++m) {
        const int row = m * 16 + l15;
        a[m] = *(const bf16x8*)((const char*)sX + row * 512 + (((4 * ks + lq) ^ (row & 7)) * 16));
      }
#pragma unroll
      for (int m = 0; m < 4; ++m)
#pragma unroll
        for (int n = 0; n < 2; ++n)
          acc[m][n] = mfma16(a[m], b1f[ks][n], acc[m][n]);
    }
    // relu + store h1 (swizzled bf16 [64][128])
#pragma unroll
    for (int m = 0; m < 4; ++m)
#pragma unroll
      for (int n = 0; n < 2; ++n)
#pragma unroll
        for (int i = 0; i < 4; ++i) {
          const int row = m * 16 + lq * 4 + i;
          const int col = wv * 32 + n * 16 + l15;
          float v = acc[m][n][i];
          v = v > 0.f ? v : 0.f;
          *(unsigned short*)((char*)sH + row * 256 +
                             ((((col >> 3) ^ (row & 7)) * 16) + (col & 7) * 2)) = f2bf(v);
        }
    __syncthreads();  // h1 ready; sX phase-1 reads done

    // ---- phase 2: msg = h1 @ W2 + b2 -> bf16 tile in sX front (swizzled) ----
    f32x4 acc2[4][2];
#pragma unroll
    for (int m = 0; m < 4; ++m)
#pragma unroll
      for (int n = 0; n < 2; ++n)
        acc2[m][n] = (f32x4){bs2[n], bs2[n], bs2[n], bs2[n]};
#pragma unroll
    for (int ks = 0; ks < 4; ++ks) {
      bf16x8 a[4];
#pragma unroll
      for (int m = 0; m < 4; ++m) {
        const int row = m * 16 + l15;
        a[m] = *(const bf16x8*)((const char*)sH + row * 256 + (((4 * ks + lq) ^ (row & 7)) * 16));
      }
#pragma unroll
      for (int m = 0; m < 4; ++m)
#pragma unroll
        for (int n = 0; n < 2; ++n)
          acc2[m][n] = mfma16(a[m], b2f[ks][n], acc2[m][n]);
    }
#pragma unroll
    for (int m = 0; m < 4; ++m)
#pragma unroll
      for (int n = 0; n < 2; ++n)
#pragma unroll
        for (int i = 0; i < 4; ++i) {
          const int row = m * 16 + lq * 4 + i;
          const int col = wv * 32 + n * 16 + l15;
          *(unsigned short*)((char*)sX + row * 256 +
                             ((((col >> 3) ^ (row & 7)) * 16) + (col & 7) * 2)) = f2bf(acc2[m][n][i]);
        }
    __syncthreads();

    // ---- out-store: row r quarter p -> fp8 at dst-sorted slot ----
    {
      const int pos = sPos[r];
      unsigned int* mrow = msg + (size_t)pos * 32;
#pragma unroll
      for (int cc = 4 * p; cc < 4 * p + 4; ++cc) {
        const u32x4 ch = *(const u32x4*)((const char*)sX + r * 256 + ((cc ^ rs) * 16));
        unsigned int w0 = 0, w1 = 0;
        float f[8];
#pragma unroll
        for (int q = 0; q < 4; ++q) {
          f[2 * q]     = __builtin_bit_cast(float, ch[q] << 16);
          f[2 * q + 1] = __builtin_bit_cast(float, ch[q] & 0xffff0000u);
        }
        w0 = __builtin_amdgcn_cvt_pk_fp8_f32(f[0], f[1], 0, false);
        w0 = __builtin_amdgcn_cvt_pk_fp8_f32(f[2], f[3], w0, true);
        w1 = __builtin_amdgcn_cvt_pk_fp8_f32(f[4], f[5], 0, false);
        w1 = __builtin_amdgcn_cvt_pk_fp8_f32(f[6], f[7], w1, true);
        *(u32x2*)(mrow + cc * 2) = (u32x2){(unsigned int)w0, (unsigned int)w1};
      }
    }
  }
}

// ---------------------------------------------------------------------------
// aggregate: sequential segmented sum over dst-sorted fp8 msg -> f32 agg
// ---------------------------------------------------------------------------
__global__ __launch_bounds__(256) void agg_kernel(
    const unsigned int* __restrict__ msg,
    const int* __restrict__ row_start,
    const int* __restrict__ cnt,
    float* __restrict__ agg)
{
  const int t = threadIdx.x;
  const int wv = t >> 6;
  const int lane = t & 63;
  const int half = lane >> 5;
  const int l32 = lane & 31;
  const int base = blockIdx.x * 64 + wv * 16;

  for (int k = 0; k < 8; ++k) {
    const int n = base + 2 * k + half;
    const bool act = n < NN;
    const int s = act ? row_start[n] : 0;
    const int c = act ? cnt[n] : 0;
    f32x4 acc = (f32x4){0.f, 0.f, 0.f, 0.f};
    for (int j = 0; j < c; ++j) {
      const int w = (int)msg[(size_t)(s + j) * 32 + l32];
      const f32x2 lo = __builtin_amdgcn_cvt_pk_f32_fp8(w, false);
      const f32x2 hi = __builtin_amdgcn_cvt_pk_f32_fp8(w, true);
      acc[0] += lo[0]; acc[1] += lo[1]; acc[2] += hi[0]; acc[3] += hi[1];
    }
    if (act) *(f32x4*)(agg + (size_t)n * 128 + l32 * 4) = acc;
  }
}

// ---------------------------------------------------------------------------
// update MLP phase 1 in full f32 (VALU): h1 = relu(X @ U1 + b1), K = 320
// ---------------------------------------------------------------------------
__global__ __launch_bounds__(128, 3) void upd1_kernel(
    const float* __restrict__ node_state,
    const float* __restrict__ agg,
    const int* __restrict__ cnt,
    const float* __restrict__ u1,    // [320][128] f32
    const float* __restrict__ b1,
    const float* __restrict__ gs,    // [64] f32
    float* __restrict__ h1out)
{
  const int n = blockIdx.x * 128 + threadIdx.x;
  const bool act = n < NN;
  const size_t row = (size_t)(act ? n : 0) * 128;

  f32x4 acc[32];
#pragma unroll
  for (int c = 0; c < 32; ++c) acc[c] = *(const f32x4*)(b1 + 4 * c);

  const float rdeg = act ? (1.0f / (float)max(cnt[n], 1)) : 0.0f;

  for (int k4 = 0; k4 < 32; ++k4) {
    const f32x4 x = *(const f32x4*)(node_state + row + 4 * k4);
#pragma unroll
    for (int kk = 0; kk < 4; ++kk) {
      const float xk = x[kk];
      const float* wr = u1 + (size_t)(4 * k4 + kk) * 128;
#pragma unroll
      for (int c = 0; c < 32; ++c) acc[c] += xk * *(const f32x4*)(wr + 4 * c);
    }
  }
  for (int k4 = 0; k4 < 32; ++k4) {
    const f32x4 x = *(const f32x4*)(agg + row + 4 * k4);
#pragma unroll
    for (int kk = 0; kk < 4; ++kk) {
      const float xk = x[kk] * rdeg;
      const float* wr = u1 + (size_t)(128 + 4 * k4 + kk) * 128;
#pragma unroll
      for (int c = 0; c < 32; ++c) acc[c] += xk * *(const f32x4*)(wr + 4 * c);
    }
  }
  for (int k = 0; k < 64; ++k) {
    const float xk = gs[k];
    const float* wr = u1 + (size_t)(256 + k) * 128;
#pragma unroll
    for (int c = 0; c < 32; ++c) acc[c] += xk * *(const f32x4*)(wr + 4 * c);
  }

  if (act) {
    float* o = h1out + (size_t)n * 128;
#pragma unroll
    for (int c = 0; c < 32; ++c) {
      f32x4 v = acc[c];
#pragma unroll
      for (int i = 0; i < 4; ++i) v[i] = v[i] > 0.f ? v[i] : 0.f;
      *(f32x4*)(o + 4 * c) = v;
    }
  }
}

// ---------------------------------------------------------------------------
// update MLP phase 2 + residual + LayerNorm, full f32 (VALU)
// ---------------------------------------------------------------------------
__global__ __launch_bounds__(128, 3) void upd2_kernel(
    const float* __restrict__ node_state,
    const float* __restrict__ h1,
    const float* __restrict__ u2,    // [128][128] f32
    const float* __restrict__ b2,
    const float* __restrict__ lng,
    const float* __restrict__ lnb,
    float* __restrict__ out)
{
  const int n = blockIdx.x * 128 + threadIdx.x;
  const bool act = n < NN;
  const size_t row = (size_t)(act ? n : 0) * 128;

  f32x4 acc[32];
#pragma unroll
  for (int c = 0; c < 32; ++c) acc[c] = *(const f32x4*)(b2 + 4 * c);

  for (int k4 = 0; k4 < 32; ++k4) {
    const f32x4 h = *(const f32x4*)(h1 + row + 4 * k4);
#pragma unroll
    for (int kk = 0; kk < 4; ++kk) {
      const float hk = h[kk];
      const float* wr = u2 + (size_t)(4 * k4 + kk) * 128;
#pragma unroll
      for (int c = 0; c < 32; ++c) acc[c] += hk * *(const f32x4*)(wr + 4 * c);
    }
  }

  if (act) {
    float s = 0.f, s2 = 0.f;
#pragma unroll
    for (int c = 0; c < 32; ++c) {
      const f32x4 nd = *(const f32x4*)(node_state + row + 4 * c);
      f32x4 x = nd + acc[c];
      acc[c] = x;
#pragma unroll
      for (int i = 0; i < 4; ++i) { s += x[i]; s2 += x[i] * x[i]; }
    }
    const float mu = s * (1.0f / 128.0f);
    float var = s2 * (1.0f / 128.0f) - mu * mu;
    var = var < 0.f ? 0.f : var;
    const float rstd = rsqrtf(var + 1e-5f);
    float* o = out + (size_t)n * 128;
#pragma unroll
    for (int c = 0; c < 32; ++c) {
      const f32x4 g = *(const f32x4*)(lng + 4 * c);
      const f32x4 b = *(const f32x4*)(lnb + 4 * c);
      f32x4 x = acc[c];
#pragma unroll
      for (int i = 0; i < 4; ++i) x[i] = (x[i] - mu) * rstd * g[i] + b[i];
      *(f32x4*)(o + 4 * c) = x;
    }
  }
}

// ---------------------------------------------------------------------------
extern "C" void kernel_launch(void* const* d_in, const int* in_sizes, int n_in,
                              void* d_out, int out_size, void* d_ws, size_t ws_size,
                              hipStream_t stream)
{
  const float* node_state = (const float*)d_in[0];
  const int* ei           = (const int*)d_in[1];   // int64 in reference -> int32 from harness
  const float* edge_state = (const float*)d_in[2];
  const float* gstate     = (const float*)d_in[3];
  const float* msg_w1     = (const float*)d_in[4];
  const float* msg_b1     = (const float*)d_in[5];
  const float* msg_w2     = (const float*)d_in[6];
  const float* msg_b2     = (const float*)d_in[7];
  const float* upd_w1     = (const float*)d_in[8];
  const float* upd_b1     = (const float*)d_in[9];
  const float* upd_w2     = (const float*)d_in[10];
  const float* upd_b2     = (const float*)d_in[11];
  const float* ln_g       = (const float*)d_in[12];
  const float* ln_b       = (const float*)d_in[13];

  char* ws = (char*)d_ws;
  // agg region (51.2 MB) double-books node_bf: node_bf is read only by
  // edge_msg_kernel; agg is first written by agg_kernel AFTER edge_msg
  // completes (stream-ordered), and is fully overwritten (no memset needed).
  float* agg              = (float*)(ws + 0);                  // 51,200,000
  unsigned short* node_bf = (unsigned short*)(ws + 0);         // 25,600,000 (aliases agg)
  int* cnt                = (int*)(ws + 51200000);             //    400,000
  int* row_start          = (int*)(ws + 51600000);             //    400,000
  int* cursor             = (int*)(ws + 52000000);             //    400,000
  int* bsum               = (int*)(ws + 52400000);             //      1,564 (pad)
  int* boff               = (int*)(ws + 52404096);             //      1,564 (pad)
  int* epos               = (int*)(ws + 52408192);             //  6,400,000
  unsigned short* w1b     = (unsigned short*)(ws + 58808192);  //     65,536
  unsigned short* w2b     = (unsigned short*)(ws + 58873728);  //     32,768
  unsigned short* gb      = (unsigned short*)(ws + 58906496);  //        128
  unsigned int* msgbuf    = (unsigned int*)(ws + 58906624);    // 204,800,000 (fp8 [NE][128])
  float* h1buf            = (float*)(ws + 58906624);           // aliases msgbuf (dead by upd1)
  (void)ws_size; (void)in_sizes; (void)n_in; (void)out_size;

  hipMemsetAsync(cnt, 0, 400000, stream);
  hipLaunchKernelGGL(convert_kernel, dim3(2048), dim3(256), 0, stream,
                     node_state, msg_w1, msg_w2, gstate, node_bf, w1b, w2b, gb);
  hipLaunchKernelGGL(hist_kernel, dim3(2048), dim3(256), 0, stream, ei, cnt);
  hipLaunchKernelGGL(scanA_kernel, dim3(NB), dim3(256), 0, stream, cnt, bsum);
  hipLaunchKernelGGL(scanB_kernel, dim3(1), dim3(512), 0, stream, bsum, boff);
  hipLaunchKernelGGL(scanC_kernel, dim3(NB), dim3(256), 0, stream, cnt, boff, row_start, cursor);
  hipLaunchKernelGGL(scatter_kernel, dim3(2048), dim3(256), 0, stream, ei, cursor, epos);
  hipLaunchKernelGGL(edge_msg_kernel, dim3(768), dim3(256), 0, stream,
                     ei, edge_state, node_bf, epos, w1b, w2b, msg_b1, msg_b2, gb, msgbuf);
  hipLaunchKernelGGL(agg_kernel, dim3((NN + 63) / 64), dim3(256), 0, stream,
                     msgbuf, row_start, cnt, agg);
  hipLaunchKernelGGL(upd1_kernel, dim3((NN + 127) / 128), dim3(128), 0, stream,
                     node_state, agg, cnt, upd_w1, upd_b1, gstate, h1buf);
  hipLaunchKernelGGL(upd2_kernel, dim3((NN + 127) / 128), dim3(128), 0, stream,
                     node_state, h1buf, upd_w2, upd_b2, ln_g, ln_b, (float*)d_out);
}